// Round 7
// baseline (159.036 us; speedup 1.0000x reference)
//
#include <hip/hip_runtime.h>
#include <hip/hip_bf16.h>
#include <cstdint>
#include <cstddef>

#define BD 2
#define SEQ 2048
#define NH 16
#define HD 64
#define IND 1024
#define QKVD 3072
#define MROWS (BD * SEQ) /* 4096 */
#define NT (SEQ / 64)    /* 32 kv tiles */

typedef __attribute__((ext_vector_type(8))) short s8v;
typedef __attribute__((ext_vector_type(4))) short s4v;
typedef __attribute__((ext_vector_type(4))) float f4v;

__device__ __forceinline__ short f2bf(float f) {
  __hip_bfloat16 h = __float2bfloat16(f);
  return *reinterpret_cast<short*>(&h);
}

__device__ __forceinline__ void async_copy16(void* lds, const void* g) {
  __builtin_amdgcn_global_load_lds(
      (const __attribute__((address_space(1))) unsigned int*)g,
      (__attribute__((address_space(3))) unsigned int*)lds, 16, 0, 0);
}

// XOR-swizzled access into a [rows][64] bf16 LDS tile (128 B rows).
__device__ __forceinline__ const s8v* lds_frag(const short* p, int row, int col) {
  int byte = (row << 7) + (col << 1);
  byte ^= ((row & 7) << 4);
  return (const s8v*)((const char*)p + byte);
}

// ---------------- prep kernels ----------------
__global__ void k_cast(const float* __restrict__ in, short* __restrict__ out, int n4) {
  int i = blockIdx.x * blockDim.x + threadIdx.x;
  if (i >= n4) return;
  float4 v = reinterpret_cast<const float4*>(in)[i];
  s4v o;
  o[0] = f2bf(v.x); o[1] = f2bf(v.y); o[2] = f2bf(v.z); o[3] = f2bf(v.w);
  reinterpret_cast<s4v*>(out)[i] = o;
}

// w: [R][C] f32 row-major  ->  wT: [C][R] bf16 row-major
__global__ void k_transpose_cast(const float* __restrict__ w, short* __restrict__ wT,
                                 int R, int C) {
  __shared__ float tile[32][33];
  int c0 = blockIdx.x * 32, r0 = blockIdx.y * 32;
  int tx = threadIdx.x, ty = threadIdx.y; // (32,8)
  #pragma unroll
  for (int j = 0; j < 32; j += 8)
    tile[ty + j][tx] = w[(size_t)(r0 + ty + j) * C + c0 + tx];
  __syncthreads();
  #pragma unroll
  for (int j = 0; j < 32; j += 8)
    wT[(size_t)(c0 + ty + j) * R + r0 + tx] = f2bf(tile[tx][ty + j]);
}

// ---------------- GEMM: C = A[M][K] * BT[N][K]^T + bias ----------------
// MODE 0: scatter bf16 into Q/K (B,H,N,D) and V TRANSPOSED (B,H,D,N);
//         Q pre-scaled by 0.125 (exact power of two)
// MODE 1: fp32 out row-major
template <int MODE>
__global__ __launch_bounds__(256) void k_gemm(const short* __restrict__ A,
                                              const short* __restrict__ BT,
                                              const float* __restrict__ bias,
                                              short* __restrict__ obf,
                                              float* __restrict__ ofl,
                                              int Mr, int Nc, int K) {
  constexpr int BM = 128, BN = 128, BK = 32;
  __shared__ short As[BM][BK];
  __shared__ short Bs[BN][BK];
  const int rm = blockIdx.x * BM, cn = blockIdx.y * BN;
  const int t = threadIdx.x, l = t & 63;
  const int wm = (t >> 6) >> 1, wn = (t >> 6) & 1;
  const int lr = l & 15, lc = l >> 4;

  f4v acc[4][4];
  #pragma unroll
  for (int m = 0; m < 4; ++m)
    #pragma unroll
    for (int n = 0; n < 4; ++n) acc[m][n] = (f4v)0.0f;

  for (int k0 = 0; k0 < K; k0 += BK) {
    __syncthreads();
    #pragma unroll
    for (int p = 0; p < 2; ++p) {
      int c = p * 256 + t;
      async_copy16(&As[c >> 2][(c & 3) * 8],
                   &A[(size_t)(rm + (c >> 2)) * K + k0 + (c & 3) * 8]);
      async_copy16(&Bs[c >> 2][(c & 3) * 8],
                   &BT[(size_t)(cn + (c >> 2)) * K + k0 + (c & 3) * 8]);
    }
    __syncthreads();
    s8v af[4], bf[4];
    #pragma unroll
    for (int m = 0; m < 4; ++m)
      af[m] = *(const s8v*)&As[wm * 64 + m * 16 + lr][lc * 8];
    #pragma unroll
    for (int n = 0; n < 4; ++n)
      bf[n] = *(const s8v*)&Bs[wn * 64 + n * 16 + lr][lc * 8];
    #pragma unroll
    for (int m = 0; m < 4; ++m)
      #pragma unroll
      for (int n = 0; n < 4; ++n)
        acc[m][n] = __builtin_amdgcn_mfma_f32_16x16x32_bf16(af[m], bf[n], acc[m][n], 0, 0, 0);
  }

  const int row0 = rm + wm * 64, col0 = cn + wn * 64;
  #pragma unroll
  for (int n = 0; n < 4; ++n) {
    const int col = col0 + n * 16 + lr;
    const float bv = bias[col];
    if (MODE == 0) {
      const int h = col / 192, rem = col % 192;
      const int wch = rem >> 6, d = rem & 63;
      const float scale = (wch == 0) ? 0.125f : 1.0f;
      short* dst = obf + (size_t)wch * ((size_t)BD * NH * SEQ * HD);
      #pragma unroll
      for (int m = 0; m < 4; ++m)
        #pragma unroll
        for (int r = 0; r < 4; ++r) {
          const int row = row0 + m * 16 + lc * 4 + r;
          const int b = row >> 11, nn = row & (SEQ - 1);
          const short val = f2bf((acc[m][n][r] + bv) * scale);
          if (wch == 2) // V stored transposed: [bh][d][n]
            dst[((size_t)(b * NH + h) * HD + d) * SEQ + nn] = val;
          else
            dst[((size_t)(b * NH + h) * SEQ + nn) * HD + d] = val;
        }
    } else {
      #pragma unroll
      for (int m = 0; m < 4; ++m)
        #pragma unroll
        for (int r = 0; r < 4; ++r) {
          const int row = row0 + m * 16 + lc * 4 + r;
          ofl[(size_t)row * Nc + col] = acc[m][n][r] + bv;
        }
    }
  }
}

// ---------------- flash attention (Q pre-scaled, V^T input) ----------------
// grid (SEQ/128, BD*NH), block 256. Each wave owns TWO 16-row q-subtiles
// (32 q total) sharing every K/V LDS fragment read — halves LDS-read traffic
// per q·kv (the R6 profile showed LDS-BW-bound: ~23 B/q·kv ≈ 46 µs floor).
// Minimum 2-phase dbuf (verified): stage-early, one __syncthreads per iter.
// Per-q-row numerics byte-identical to R2/R6.
__global__ __launch_bounds__(256) void k_attn(const short* __restrict__ Qw,
                                              const short* __restrict__ Kw,
                                              const short* __restrict__ Vt_g,
                                              short* __restrict__ AO) {
  const int qb = blockIdx.x, bh = blockIdx.y;
  const size_t base = (size_t)bh * SEQ * HD;
  const int t = threadIdx.x, l = t & 63, w = t >> 6;
  const int lr = l & 15, lc = l >> 4;
  __shared__ short Ks[2][64 * 64];
  __shared__ short Vt[2][64 * 64];
  __shared__ short Ps[4][2][16 * 64];  // per-wave, per-subtile P
  const int q0 = qb * 128 + w * 16;    // subtile u adds u*64

  // per-thread staging offsets: chunk c = p*256+t; source chunk pre-swizzled
  int ldsOff[2], kOff[2], vOff[2];
  #pragma unroll
  for (int p = 0; p < 2; ++p) {
    const int c = p * 256 + t;
    const int row = c >> 3, ch = (c & 7) ^ (row & 7);
    ldsOff[p] = c * 16;
    kOff[p] = row * HD + ch * 8;   // within K tile (rows are kv)
    vOff[p] = row * SEQ + ch * 8;  // within V^T (rows are d, + kv col offset)
  }
  const short* Kb = Kw + base;
  const short* Vb = Vt_g + base;

  s8v qf[2][2];
  #pragma unroll
  for (int u = 0; u < 2; ++u)
    #pragma unroll
    for (int s = 0; s < 2; ++s)
      qf[u][s] = *(const s8v*)&Qw[base + (size_t)(q0 + u * 64 + lr) * HD + s * 32 + lc * 8];

  f4v of[2][4];
  #pragma unroll
  for (int u = 0; u < 2; ++u)
    #pragma unroll
    for (int j = 0; j < 4; ++j) of[u][j] = (f4v)0.0f;
  float Mx[2] = {-3.0e38f, -3.0e38f}, Ls[2] = {0.0f, 0.0f};

  auto STAGE = [&](int buf, int tile) {
    const size_t kv = (size_t)tile * 64;
    #pragma unroll
    for (int p = 0; p < 2; ++p)
      async_copy16((char*)Ks[buf] + ldsOff[p], Kb + kv * HD + kOff[p]);
    #pragma unroll
    for (int p = 0; p < 2; ++p)
      async_copy16((char*)Vt[buf] + ldsOff[p], Vb + kv + vOff[p]);
  };

  auto COMPUTE = [&](const short* ksB, const short* vtB) {
    // S^T = K * Q^T per subtile: lane holds S[q=lr][kv = j*16 + lc*4 + r]
    f4v st[2][4];
    #pragma unroll
    for (int u = 0; u < 2; ++u)
      #pragma unroll
      for (int j = 0; j < 4; ++j) st[u][j] = (f4v)0.0f;
    #pragma unroll
    for (int j = 0; j < 4; ++j)
      #pragma unroll
      for (int s = 0; s < 2; ++s) {
        s8v kf = *lds_frag(ksB, j * 16 + lr, s * 32 + lc * 8); // shared by both subtiles
        #pragma unroll
        for (int u = 0; u < 2; ++u)
          st[u][j] = __builtin_amdgcn_mfma_f32_16x16x32_bf16(kf, qf[u][s], st[u][j], 0, 0, 0);
      }

    // online softmax per q-row, independent per subtile (order-identical to R2)
    #pragma unroll
    for (int u = 0; u < 2; ++u) {
      float pm = -3.0e38f;
      #pragma unroll
      for (int j = 0; j < 4; ++j)
        #pragma unroll
        for (int r = 0; r < 4; ++r) pm = fmaxf(pm, st[u][j][r]);
      pm = fmaxf(pm, __shfl_xor(pm, 16));
      pm = fmaxf(pm, __shfl_xor(pm, 32));
      const float Mn = fmaxf(Mx[u], pm);
      const float alpha = __expf(Mx[u] - Mn);
      float rs = 0.0f;
      #pragma unroll
      for (int j = 0; j < 4; ++j) {
        s4v pk;
        #pragma unroll
        for (int r = 0; r < 4; ++r) {
          const float p = __expf(st[u][j][r] - Mn);
          rs += p;
          pk[r] = f2bf(p);
        }
        int byte = (lr << 7) + ((j * 16 + lc * 4) << 1);
        byte ^= ((lr & 7) << 4);
        *(s4v*)((char*)&Ps[w][u][0] + byte) = pk;
      }
      rs += __shfl_xor(rs, 16);
      rs += __shfl_xor(rs, 32);
      Ls[u] = Ls[u] * alpha + rs;
      Mx[u] = Mn;

      // rescale O (O rows are q = lc*4 + r -> fetch alpha from lane q)
      float al[4];
      #pragma unroll
      for (int r = 0; r < 4; ++r) al[r] = __shfl(alpha, lc * 4 + r);
      #pragma unroll
      for (int jd = 0; jd < 4; ++jd)
        #pragma unroll
        for (int r = 0; r < 4; ++r) of[u][jd][r] *= al[r];
    }

    // ensure P ds_writes complete (and fence compiler ordering) before PV reads
    asm volatile("s_waitcnt lgkmcnt(0)" ::: "memory");

    // O += P * V  (V fragment shared by both subtiles)
    #pragma unroll
    for (int s = 0; s < 2; ++s) {
      s8v pf[2];
      #pragma unroll
      for (int u = 0; u < 2; ++u)
        pf[u] = *lds_frag(&Ps[w][u][0], lr, s * 32 + lc * 8);
      #pragma unroll
      for (int jd = 0; jd < 4; ++jd) {
        s8v vf = *lds_frag(vtB, jd * 16 + lr, s * 32 + lc * 8);
        #pragma unroll
        for (int u = 0; u < 2; ++u)
          of[u][jd] = __builtin_amdgcn_mfma_f32_16x16x32_bf16(pf[u], vf, of[u][jd], 0, 0, 0);
      }
    }
  };

  STAGE(0, 0);
  __syncthreads(); // tile 0 staged (drains vmcnt to 0 + barrier)
  int cur = 0;
  for (int tt = 0; tt < NT - 1; ++tt) {
    STAGE(cur ^ 1, tt + 1);   // issue early: HBM latency hides under COMPUTE
    COMPUTE(Ks[cur], Vt[cur]);
    __syncthreads();          // drains stage writes; all reads of buf[cur] done
    cur ^= 1;
  }
  COMPUTE(Ks[cur], Vt[cur]);

  const int b = bh >> 4, h = bh & 15;
  #pragma unroll
  for (int u = 0; u < 2; ++u) {
    float li[4];
    #pragma unroll
    for (int r = 0; r < 4; ++r) li[r] = 1.0f / __shfl(Ls[u], lc * 4 + r);
    #pragma unroll
    for (int jd = 0; jd < 4; ++jd)
      #pragma unroll
      for (int r = 0; r < 4; ++r) {
        const int nq = q0 + u * 64 + lc * 4 + r;
        AO[(size_t)(b * SEQ + nq) * (NH * HD) + h * HD + jd * 16 + lr] =
            f2bf(of[u][jd][r] * li[r]);
      }
  }
}

// ---------------- launch ----------------
extern "C" void kernel_launch(void* const* d_in, const int* in_sizes, int n_in,
                              void* d_out, int out_size, void* d_ws, size_t ws_size,
                              hipStream_t stream) {
  const float* x      = (const float*)d_in[0];
  const float* w_qkv  = (const float*)d_in[1];
  const float* b_qkv  = (const float*)d_in[2];
  const float* w_proj = (const float*)d_in[3];
  const float* b_proj = (const float*)d_in[4];
  float* out = (float*)d_out;

  char* ws = (char*)d_ws;
  short* xb  = (short*)(ws);                 //  8 MB  x as bf16 [4096][1024]
  short* wqT = (short*)(ws + 8388608);       //  6 MB  w_qkv^T bf16 [3072][1024]
  short* wpT = (short*)(ws + 14680064);      //  2 MB  w_proj^T bf16 [1024][1024]
  short* Qw  = (short*)(ws + 16777216);      //  8 MB  (B,H,N,D) bf16, pre-scaled
  short* Kw  = (short*)(ws + 25165824);      //  8 MB  (B,H,N,D)
  short* Vtg = (short*)(ws + 33554432);      //  8 MB  (B,H,D,N)  V transposed
  short* AO  = (short*)(ws + 41943040);      //  8 MB  attn out (B,N,H*D) bf16

  k_cast<<<(MROWS * IND / 4 + 255) / 256, 256, 0, stream>>>(x, xb, MROWS * IND / 4);
  dim3 tb(32, 8);
  k_transpose_cast<<<dim3(QKVD / 32, IND / 32), tb, 0, stream>>>(w_qkv, wqT, IND, QKVD);
  k_transpose_cast<<<dim3(IND / 32, IND / 32), tb, 0, stream>>>(w_proj, wpT, IND, IND);

  k_gemm<0><<<dim3(MROWS / 128, QKVD / 128), 256, 0, stream>>>(
      xb, wqT, b_qkv, Qw, nullptr, MROWS, QKVD, IND);
  k_attn<<<dim3(SEQ / 128, BD * NH), 256, 0, stream>>>(Qw, Kw, Vtg, AO);
  k_gemm<1><<<dim3(MROWS / 128, IND / 128), 256, 0, stream>>>(
      AO, wpT, b_proj, nullptr, out, MROWS, IND, IND);
}

// Round 8
// 156.557 us; speedup vs baseline: 1.0158x; 1.0158x over previous
//
#include <hip/hip_runtime.h>
#include <hip/hip_bf16.h>
#include <cstdint>
#include <cstddef>

#define BD 2
#define SEQ 2048
#define NH 16
#define HD 64
#define IND 1024
#define QKVD 3072
#define MROWS (BD * SEQ) /* 4096 */
#define NSPLIT 2
#define TILES_PER_SPLIT (SEQ / 64 / NSPLIT) /* 16 */

typedef __attribute__((ext_vector_type(8))) short s8v;
typedef __attribute__((ext_vector_type(4))) short s4v;
typedef __attribute__((ext_vector_type(4))) float f4v;

__device__ __forceinline__ short f2bf(float f) {
  __hip_bfloat16 h = __float2bfloat16(f);
  return *reinterpret_cast<short*>(&h);
}

__device__ __forceinline__ void async_copy16(void* lds, const void* g) {
  __builtin_amdgcn_global_load_lds(
      (const __attribute__((address_space(1))) unsigned int*)g,
      (__attribute__((address_space(3))) unsigned int*)lds, 16, 0, 0);
}

// XOR-swizzled access into a [rows][64] bf16 LDS tile (128 B rows).
__device__ __forceinline__ const s8v* lds_frag(const short* p, int row, int col) {
  int byte = (row << 7) + (col << 1);
  byte ^= ((row & 7) << 4);
  return (const s8v*)((const char*)p + byte);
}

// ---------------- prep kernels ----------------
__global__ void k_cast(const float* __restrict__ in, short* __restrict__ out, int n4) {
  int i = blockIdx.x * blockDim.x + threadIdx.x;
  if (i >= n4) return;
  float4 v = reinterpret_cast<const float4*>(in)[i];
  s4v o;
  o[0] = f2bf(v.x); o[1] = f2bf(v.y); o[2] = f2bf(v.z); o[3] = f2bf(v.w);
  reinterpret_cast<s4v*>(out)[i] = o;
}

// w: [R][C] f32 row-major  ->  wT: [C][R] bf16 row-major
__global__ void k_transpose_cast(const float* __restrict__ w, short* __restrict__ wT,
                                 int R, int C) {
  __shared__ float tile[32][33];
  int c0 = blockIdx.x * 32, r0 = blockIdx.y * 32;
  int tx = threadIdx.x, ty = threadIdx.y; // (32,8)
  #pragma unroll
  for (int j = 0; j < 32; j += 8)
    tile[ty + j][tx] = w[(size_t)(r0 + ty + j) * C + c0 + tx];
  __syncthreads();
  #pragma unroll
  for (int j = 0; j < 32; j += 8)
    wT[(size_t)(c0 + ty + j) * R + r0 + tx] = f2bf(tile[tx][ty + j]);
}

// ---------------- GEMM: C = A[M][K] * BT[N][K]^T + bias ----------------
// MODE 0: scatter bf16 into Q/K (B,H,N,D) and V TRANSPOSED (B,H,D,N);
//         Q pre-scaled by 0.125 (exact power of two)
// MODE 1: fp32 out row-major
template <int MODE>
__global__ __launch_bounds__(256) void k_gemm(const short* __restrict__ A,
                                              const short* __restrict__ BT,
                                              const float* __restrict__ bias,
                                              short* __restrict__ obf,
                                              float* __restrict__ ofl,
                                              int Mr, int Nc, int K) {
  constexpr int BM = 128, BN = 128, BK = 32;
  __shared__ short As[BM][BK];
  __shared__ short Bs[BN][BK];
  const int rm = blockIdx.x * BM, cn = blockIdx.y * BN;
  const int t = threadIdx.x, l = t & 63;
  const int wm = (t >> 6) >> 1, wn = (t >> 6) & 1;
  const int lr = l & 15, lc = l >> 4;

  f4v acc[4][4];
  #pragma unroll
  for (int m = 0; m < 4; ++m)
    #pragma unroll
    for (int n = 0; n < 4; ++n) acc[m][n] = (f4v)0.0f;

  for (int k0 = 0; k0 < K; k0 += BK) {
    __syncthreads();
    #pragma unroll
    for (int p = 0; p < 2; ++p) {
      int c = p * 256 + t;
      async_copy16(&As[c >> 2][(c & 3) * 8],
                   &A[(size_t)(rm + (c >> 2)) * K + k0 + (c & 3) * 8]);
      async_copy16(&Bs[c >> 2][(c & 3) * 8],
                   &BT[(size_t)(cn + (c >> 2)) * K + k0 + (c & 3) * 8]);
    }
    __syncthreads();
    s8v af[4], bf[4];
    #pragma unroll
    for (int m = 0; m < 4; ++m)
      af[m] = *(const s8v*)&As[wm * 64 + m * 16 + lr][lc * 8];
    #pragma unroll
    for (int n = 0; n < 4; ++n)
      bf[n] = *(const s8v*)&Bs[wn * 64 + n * 16 + lr][lc * 8];
    #pragma unroll
    for (int m = 0; m < 4; ++m)
      #pragma unroll
      for (int n = 0; n < 4; ++n)
        acc[m][n] = __builtin_amdgcn_mfma_f32_16x16x32_bf16(af[m], bf[n], acc[m][n], 0, 0, 0);
  }

  const int row0 = rm + wm * 64, col0 = cn + wn * 64;
  #pragma unroll
  for (int n = 0; n < 4; ++n) {
    const int col = col0 + n * 16 + lr;
    const float bv = bias[col];
    if (MODE == 0) {
      const int h = col / 192, rem = col % 192;
      const int wch = rem >> 6, d = rem & 63;
      const float scale = (wch == 0) ? 0.125f : 1.0f;
      short* dst = obf + (size_t)wch * ((size_t)BD * NH * SEQ * HD);
      #pragma unroll
      for (int m = 0; m < 4; ++m)
        #pragma unroll
        for (int r = 0; r < 4; ++r) {
          const int row = row0 + m * 16 + lc * 4 + r;
          const int b = row >> 11, nn = row & (SEQ - 1);
          const short val = f2bf((acc[m][n][r] + bv) * scale);
          if (wch == 2) // V stored transposed: [bh][d][n]
            dst[((size_t)(b * NH + h) * HD + d) * SEQ + nn] = val;
          else
            dst[((size_t)(b * NH + h) * SEQ + nn) * HD + d] = val;
        }
    } else {
      #pragma unroll
      for (int m = 0; m < 4; ++m)
        #pragma unroll
        for (int r = 0; r < 4; ++r) {
          const int row = row0 + m * 16 + lc * 4 + r;
          ofl[(size_t)row * Nc + col] = acc[m][n][r] + bv;
        }
    }
  }
}

// ---------------- flash attention, KV-SPLIT (Q pre-scaled, V^T input) ------
// grid (SEQ/64, BD*NH, NSPLIT), block 256 (4 waves x 16 q rows). Each block
// covers 1024 kv (16 tiles of 64) and emits UNNORMALIZED partial O (f32) plus
// per-row (m, l) for a combine pass. Single-buffered LDS (24 KB -> 6 blk/CU,
// 2048 blocks -> 8/CU grid) to raise occupancy 2x over R6 (latency-bound).
// Staging schedule and COMPUTE are the R2-verified code verbatim.
__global__ __launch_bounds__(256, 6) void k_attn(const short* __restrict__ Qw,
                                                 const short* __restrict__ Kw,
                                                 const short* __restrict__ Vt_g,
                                                 float* __restrict__ OP0,
                                                 float* __restrict__ OP1,
                                                 float* __restrict__ ML) {
  const int qb = blockIdx.x, bh = blockIdx.y, split = blockIdx.z;
  const size_t base = (size_t)bh * SEQ * HD;
  const int t = threadIdx.x, l = t & 63, w = t >> 6;
  const int lr = l & 15, lc = l >> 4;
  __shared__ short Ks[64 * 64];
  __shared__ short Vt[64 * 64];
  __shared__ short Ps[4][16 * 64];
  const int q0 = qb * 64 + w * 16;

  // per-thread staging offsets: chunk c = p*256+t; source chunk pre-swizzled
  int ldsOff[2], kOff[2], vOff[2];
  #pragma unroll
  for (int p = 0; p < 2; ++p) {
    const int c = p * 256 + t;
    const int row = c >> 3, ch = (c & 7) ^ (row & 7);
    ldsOff[p] = c * 16;
    kOff[p] = row * HD + ch * 8;   // within K tile (rows are kv)
    vOff[p] = row * SEQ + ch * 8;  // within V^T (rows are d, + kv col offset)
  }
  const short* Kb = Kw + base;
  const short* Vb = Vt_g + base;

  s8v qf[2];
  #pragma unroll
  for (int s = 0; s < 2; ++s)
    qf[s] = *(const s8v*)&Qw[base + (size_t)(q0 + lr) * HD + s * 32 + lc * 8];

  f4v of[4];
  #pragma unroll
  for (int j = 0; j < 4; ++j) of[j] = (f4v)0.0f;
  float Mx = -3.0e38f, Ls = 0.0f;
  short* Pw = &Ps[w][0];

  for (int tt = 0; tt < TILES_PER_SPLIT; ++tt) {
    const size_t kv = (size_t)(split * TILES_PER_SPLIT + tt) * 64;
    __syncthreads();
    #pragma unroll
    for (int p = 0; p < 2; ++p)
      async_copy16((char*)Ks + ldsOff[p], Kb + kv * HD + kOff[p]);
    #pragma unroll
    for (int p = 0; p < 2; ++p)
      async_copy16((char*)Vt + ldsOff[p], Vb + kv + vOff[p]);
    __syncthreads();

    // S^T = K * Q^T : lane holds S[q=lr][kv = j*16 + lc*4 + r]
    f4v st[4];
    #pragma unroll
    for (int j = 0; j < 4; ++j) st[j] = (f4v)0.0f;
    #pragma unroll
    for (int j = 0; j < 4; ++j)
      #pragma unroll
      for (int s = 0; s < 2; ++s) {
        s8v kf = *lds_frag(Ks, j * 16 + lr, s * 32 + lc * 8);
        st[j] = __builtin_amdgcn_mfma_f32_16x16x32_bf16(kf, qf[s], st[j], 0, 0, 0);
      }

    // online softmax per q-row (= lane lr, replicated over 4 groups)
    float pm = -3.0e38f;
    #pragma unroll
    for (int j = 0; j < 4; ++j)
      #pragma unroll
      for (int r = 0; r < 4; ++r) pm = fmaxf(pm, st[j][r]);
    pm = fmaxf(pm, __shfl_xor(pm, 16));
    pm = fmaxf(pm, __shfl_xor(pm, 32));
    const float Mn = fmaxf(Mx, pm);
    const float alpha = __expf(Mx - Mn);
    float rs = 0.0f;
    #pragma unroll
    for (int j = 0; j < 4; ++j) {
      s4v pk;
      #pragma unroll
      for (int r = 0; r < 4; ++r) {
        const float p = __expf(st[j][r] - Mn);
        rs += p;
        pk[r] = f2bf(p);
      }
      int byte = (lr << 7) + ((j * 16 + lc * 4) << 1);
      byte ^= ((lr & 7) << 4);
      *(s4v*)((char*)Pw + byte) = pk;
    }
    rs += __shfl_xor(rs, 16);
    rs += __shfl_xor(rs, 32);
    Ls = Ls * alpha + rs;
    Mx = Mn;

    // rescale O (O rows are q = lc*4 + r -> fetch alpha from lane q)
    float al[4];
    #pragma unroll
    for (int r = 0; r < 4; ++r) al[r] = __shfl(alpha, lc * 4 + r);
    #pragma unroll
    for (int jd = 0; jd < 4; ++jd)
      #pragma unroll
      for (int r = 0; r < 4; ++r) of[jd][r] *= al[r];

    // ensure P ds_writes complete (and fence compiler ordering) before PV reads
    asm volatile("s_waitcnt lgkmcnt(0)" ::: "memory");

    // O += P * V
    #pragma unroll
    for (int s = 0; s < 2; ++s) {
      s8v pf = *lds_frag(Pw, lr, s * 32 + lc * 8);
      #pragma unroll
      for (int jd = 0; jd < 4; ++jd) {
        s8v vf = *lds_frag(Vt, jd * 16 + lr, s * 32 + lc * 8);
        of[jd] = __builtin_amdgcn_mfma_f32_16x16x32_bf16(pf, vf, of[jd], 0, 0, 0);
      }
    }
  }

  // store UNNORMALIZED partial O (f32) + per-row (m, l)
  float* OP = split ? OP1 : OP0;
  #pragma unroll
  for (int jd = 0; jd < 4; ++jd)
    #pragma unroll
    for (int r = 0; r < 4; ++r)
      OP[((size_t)bh * SEQ + q0 + lc * 4 + r) * HD + jd * 16 + lr] = of[jd][r];
  if (lc == 0) {
    float2 ml = make_float2(Mx, Ls);
    *reinterpret_cast<float2*>(
        &ML[((size_t)split * BD * NH * SEQ + (size_t)bh * SEQ + q0 + lr) * 2]) = ml;
  }
}

// ---------------- combine split halves -> AO bf16 (B,N,H*D) ----------------
__global__ __launch_bounds__(256) void k_comb(const float* __restrict__ OP0,
                                              const float* __restrict__ OP1,
                                              const float* __restrict__ ML,
                                              short* __restrict__ AO) {
  const int gid = blockIdx.x * 256 + threadIdx.x; // one (row, 16d-chunk) each
  const int row = gid >> 2, c = gid & 3;          // rows = 32*2048
  const int bh = row >> 11, q = row & (SEQ - 1);
  const float2 ml1 = *reinterpret_cast<const float2*>(&ML[(size_t)row * 2]);
  const float2 ml2 = *reinterpret_cast<const float2*>(
      &ML[((size_t)BD * NH * SEQ + row) * 2]);
  const float M = fmaxf(ml1.x, ml2.x);
  const float w1 = __expf(ml1.x - M), w2 = __expf(ml2.x - M);
  const float inv = 1.0f / (w1 * ml1.y + w2 * ml2.y);
  const int b = bh >> 4, h = bh & 15;
  short* dst = &AO[((size_t)(b * SEQ + q) * (NH * HD)) + h * HD + c * 16];
  const size_t src = (size_t)row * HD + c * 16;
  #pragma unroll
  for (int i = 0; i < 4; ++i) {
    float4 a = reinterpret_cast<const float4*>(&OP0[src])[i];
    float4 bvv = reinterpret_cast<const float4*>(&OP1[src])[i];
    s4v o;
    o[0] = f2bf((w1 * a.x + w2 * bvv.x) * inv);
    o[1] = f2bf((w1 * a.y + w2 * bvv.y) * inv);
    o[2] = f2bf((w1 * a.z + w2 * bvv.z) * inv);
    o[3] = f2bf((w1 * a.w + w2 * bvv.w) * inv);
    reinterpret_cast<s4v*>(dst)[i] = o;
  }
}

// ---------------- launch ----------------
extern "C" void kernel_launch(void* const* d_in, const int* in_sizes, int n_in,
                              void* d_out, int out_size, void* d_ws, size_t ws_size,
                              hipStream_t stream) {
  const float* x      = (const float*)d_in[0];
  const float* w_qkv  = (const float*)d_in[1];
  const float* b_qkv  = (const float*)d_in[2];
  const float* w_proj = (const float*)d_in[3];
  const float* b_proj = (const float*)d_in[4];
  float* out = (float*)d_out;

  // ws layout (MiB offsets). xb/wqT are dead after the QKV GEMM and are
  // overlaid by OP1 (attn partial half 1). OP0 reuses d_out (16 MiB f32),
  // which the proj GEMM overwrites last.
  char* ws = (char*)d_ws;
  short* wpT = (short*)(ws);                  //  2 MiB  w_proj^T bf16
  short* Qw  = (short*)(ws + (2u << 20));     //  8 MiB  Q (B,H,N,D) pre-scaled
  short* Kw  = (short*)(ws + (10u << 20));    //  8 MiB  K (B,H,N,D)
  short* Vtg = (short*)(ws + (18u << 20));    //  8 MiB  V^T (B,H,D,N)
  short* AO  = (short*)(ws + (26u << 20));    //  8 MiB  attn out bf16 (B,N,H*D)
  short* xb  = (short*)(ws + (34u << 20));    //  8 MiB  x bf16 [dead after GEMM0]
  short* wqT = (short*)(ws + (42u << 20));    //  6 MiB  w_qkv^T [dead after GEMM0]
  float* OP1 = (float*)(ws + (34u << 20));    // 16 MiB  attn partial 1 (overlay)
  float* ML  = (float*)(ws + (50u << 20));    //  1 MiB  (m,l) pairs, both splits
  float* OP0 = (float*)d_out;                 // 16 MiB  attn partial 0

  k_cast<<<(MROWS * IND / 4 + 255) / 256, 256, 0, stream>>>(x, xb, MROWS * IND / 4);
  dim3 tb(32, 8);
  k_transpose_cast<<<dim3(QKVD / 32, IND / 32), tb, 0, stream>>>(w_qkv, wqT, IND, QKVD);
  k_transpose_cast<<<dim3(IND / 32, IND / 32), tb, 0, stream>>>(w_proj, wpT, IND, IND);

  k_gemm<0><<<dim3(MROWS / 128, QKVD / 128), 256, 0, stream>>>(
      xb, wqT, b_qkv, Qw, nullptr, MROWS, QKVD, IND);
  k_attn<<<dim3(SEQ / 64, BD * NH, NSPLIT), 256, 0, stream>>>(Qw, Kw, Vtg, OP0, OP1, ML);
  k_comb<<<(BD * NH * SEQ * 4) / 256, 256, 0, stream>>>(OP0, OP1, ML, AO);
  k_gemm<1><<<dim3(MROWS / 128, IND / 128), 256, 0, stream>>>(
      AO, wpT, b_proj, nullptr, out, MROWS, IND, IND);
}

// Round 9
// 145.846 us; speedup vs baseline: 1.0904x; 1.0734x over previous
//
#include <hip/hip_runtime.h>
#include <hip/hip_bf16.h>
#include <cstdint>
#include <cstddef>

#define BD 2
#define SEQ 2048
#define NH 16
#define HD 64
#define IND 1024
#define QKVD 3072
#define MROWS (BD * SEQ) /* 4096 */
#define NSPLIT 2
#define TILES_PER_SPLIT (SEQ / 64 / NSPLIT) /* 16 */

typedef __attribute__((ext_vector_type(8))) short s8v;
typedef __attribute__((ext_vector_type(4))) short s4v;
typedef __attribute__((ext_vector_type(4))) float f4v;

__device__ __forceinline__ short f2bf(float f) {
  __hip_bfloat16 h = __float2bfloat16(f);
  return *reinterpret_cast<short*>(&h);
}

__device__ __forceinline__ void async_copy16(void* lds, const void* g) {
  __builtin_amdgcn_global_load_lds(
      (const __attribute__((address_space(1))) unsigned int*)g,
      (__attribute__((address_space(3))) unsigned int*)lds, 16, 0, 0);
}

// XOR-swizzled access into a [rows][64] bf16 LDS tile (128 B rows).
__device__ __forceinline__ const s8v* lds_frag(const short* p, int row, int col) {
  int byte = (row << 7) + (col << 1);
  byte ^= ((row & 7) << 4);
  return (const s8v*)((const char*)p + byte);
}

// ---------------- prep kernels ----------------
__global__ void k_cast(const float* __restrict__ in, short* __restrict__ out, int n4) {
  int i = blockIdx.x * blockDim.x + threadIdx.x;
  if (i >= n4) return;
  float4 v = reinterpret_cast<const float4*>(in)[i];
  s4v o;
  o[0] = f2bf(v.x); o[1] = f2bf(v.y); o[2] = f2bf(v.z); o[3] = f2bf(v.w);
  reinterpret_cast<s4v*>(out)[i] = o;
}

// w: [R][C] f32 row-major  ->  wT: [C][R] bf16 row-major
__global__ void k_transpose_cast(const float* __restrict__ w, short* __restrict__ wT,
                                 int R, int C) {
  __shared__ float tile[32][33];
  int c0 = blockIdx.x * 32, r0 = blockIdx.y * 32;
  int tx = threadIdx.x, ty = threadIdx.y; // (32,8)
  #pragma unroll
  for (int j = 0; j < 32; j += 8)
    tile[ty + j][tx] = w[(size_t)(r0 + ty + j) * C + c0 + tx];
  __syncthreads();
  #pragma unroll
  for (int j = 0; j < 32; j += 8)
    wT[(size_t)(c0 + ty + j) * R + r0 + tx] = f2bf(tile[tx][ty + j]);
}

// ---------------- GEMM: C = A[M][K] * BT[N][K]^T + bias ----------------
// BK=64 (halves barrier-drain count vs BK=32) with T2 XOR-swizzled LDS:
// 128 B rows + byte^((row&7)<<4) -> conflict-free ds_read_b128 (was 8-way).
// MODE 0: scatter bf16 into Q/K (B,H,N,D) and V TRANSPOSED (B,H,D,N);
//         Q pre-scaled by 0.125 (exact power of two)
// MODE 1: fp32 out row-major
template <int MODE>
__global__ __launch_bounds__(256) void k_gemm(const short* __restrict__ A,
                                              const short* __restrict__ BT,
                                              const float* __restrict__ bias,
                                              short* __restrict__ obf,
                                              float* __restrict__ ofl,
                                              int Mr, int Nc, int K) {
  constexpr int BM = 128, BN = 128, BK = 64;
  __shared__ short As[BM * BK];
  __shared__ short Bs[BN * BK];
  const int rm = blockIdx.x * BM, cn = blockIdx.y * BN;
  const int t = threadIdx.x, l = t & 63;
  const int wm = (t >> 6) >> 1, wn = (t >> 6) & 1;
  const int lr = l & 15, lc = l >> 4;

  // staging chunks: c = p*256+t; row = c>>3 (8 chunks/row), source pre-swizzled
  int sRow[4], sCh[4];
  #pragma unroll
  for (int p = 0; p < 4; ++p) {
    const int c = p * 256 + t;
    sRow[p] = c >> 3;
    sCh[p] = ((c & 7) ^ (sRow[p] & 7)) * 8;
  }

  f4v acc[4][4];
  #pragma unroll
  for (int m = 0; m < 4; ++m)
    #pragma unroll
    for (int n = 0; n < 4; ++n) acc[m][n] = (f4v)0.0f;

  for (int k0 = 0; k0 < K; k0 += BK) {
    __syncthreads();
    #pragma unroll
    for (int p = 0; p < 4; ++p) {
      const int c = p * 256 + t;
      async_copy16((char*)As + c * 16, &A[(size_t)(rm + sRow[p]) * K + k0 + sCh[p]]);
      async_copy16((char*)Bs + c * 16, &BT[(size_t)(cn + sRow[p]) * K + k0 + sCh[p]]);
    }
    __syncthreads();
    #pragma unroll
    for (int ks = 0; ks < 2; ++ks) {
      s8v af[4], bf[4];
      #pragma unroll
      for (int m = 0; m < 4; ++m)
        af[m] = *lds_frag(As, wm * 64 + m * 16 + lr, ks * 32 + lc * 8);
      #pragma unroll
      for (int n = 0; n < 4; ++n)
        bf[n] = *lds_frag(Bs, wn * 64 + n * 16 + lr, ks * 32 + lc * 8);
      #pragma unroll
      for (int m = 0; m < 4; ++m)
        #pragma unroll
        for (int n = 0; n < 4; ++n)
          acc[m][n] = __builtin_amdgcn_mfma_f32_16x16x32_bf16(af[m], bf[n], acc[m][n], 0, 0, 0);
    }
  }

  const int row0 = rm + wm * 64, col0 = cn + wn * 64;
  #pragma unroll
  for (int n = 0; n < 4; ++n) {
    const int col = col0 + n * 16 + lr;
    const float bv = bias[col];
    if (MODE == 0) {
      const int h = col / 192, rem = col % 192;
      const int wch = rem >> 6, d = rem & 63;
      const float scale = (wch == 0) ? 0.125f : 1.0f;
      short* dst = obf + (size_t)wch * ((size_t)BD * NH * SEQ * HD);
      #pragma unroll
      for (int m = 0; m < 4; ++m)
        #pragma unroll
        for (int r = 0; r < 4; ++r) {
          const int row = row0 + m * 16 + lc * 4 + r;
          const int b = row >> 11, nn = row & (SEQ - 1);
          const short val = f2bf((acc[m][n][r] + bv) * scale);
          if (wch == 2) // V stored transposed: [bh][d][n]
            dst[((size_t)(b * NH + h) * HD + d) * SEQ + nn] = val;
          else
            dst[((size_t)(b * NH + h) * SEQ + nn) * HD + d] = val;
        }
    } else {
      #pragma unroll
      for (int m = 0; m < 4; ++m)
        #pragma unroll
        for (int r = 0; r < 4; ++r) {
          const int row = row0 + m * 16 + lc * 4 + r;
          ofl[(size_t)row * Nc + col] = acc[m][n][r] + bv;
        }
    }
  }
}

// ---------------- flash attention, KV-SPLIT (Q pre-scaled, V^T input) ------
// grid (SEQ/64, BD*NH, NSPLIT), block 256 (4 waves x 16 q rows). R8-verified
// structure; this round only cuts VALU: tree max/sum reductions (shorter dep
// chains) + T13 defer-max (skip rescale while pm <= Mx+8; P bounded by e^8).
__global__ __launch_bounds__(256, 6) void k_attn(const short* __restrict__ Qw,
                                                 const short* __restrict__ Kw,
                                                 const short* __restrict__ Vt_g,
                                                 float* __restrict__ OP0,
                                                 float* __restrict__ OP1,
                                                 float* __restrict__ ML) {
  const int qb = blockIdx.x, bh = blockIdx.y, split = blockIdx.z;
  const size_t base = (size_t)bh * SEQ * HD;
  const int t = threadIdx.x, l = t & 63, w = t >> 6;
  const int lr = l & 15, lc = l >> 4;
  __shared__ short Ks[64 * 64];
  __shared__ short Vt[64 * 64];
  __shared__ short Ps[4][16 * 64];
  const int q0 = qb * 64 + w * 16;

  int ldsOff[2], kOff[2], vOff[2];
  #pragma unroll
  for (int p = 0; p < 2; ++p) {
    const int c = p * 256 + t;
    const int row = c >> 3, ch = (c & 7) ^ (row & 7);
    ldsOff[p] = c * 16;
    kOff[p] = row * HD + ch * 8;
    vOff[p] = row * SEQ + ch * 8;
  }
  const short* Kb = Kw + base;
  const short* Vb = Vt_g + base;

  s8v qf[2];
  #pragma unroll
  for (int s = 0; s < 2; ++s)
    qf[s] = *(const s8v*)&Qw[base + (size_t)(q0 + lr) * HD + s * 32 + lc * 8];

  f4v of[4];
  #pragma unroll
  for (int j = 0; j < 4; ++j) of[j] = (f4v)0.0f;
  float Mx = -3.0e38f, Ls = 0.0f;
  short* Pw = &Ps[w][0];

  for (int tt = 0; tt < TILES_PER_SPLIT; ++tt) {
    const size_t kv = (size_t)(split * TILES_PER_SPLIT + tt) * 64;
    __syncthreads();
    #pragma unroll
    for (int p = 0; p < 2; ++p)
      async_copy16((char*)Ks + ldsOff[p], Kb + kv * HD + kOff[p]);
    #pragma unroll
    for (int p = 0; p < 2; ++p)
      async_copy16((char*)Vt + ldsOff[p], Vb + kv + vOff[p]);
    __syncthreads();

    // S^T = K * Q^T : lane holds S[q=lr][kv = j*16 + lc*4 + r]
    f4v st[4];
    #pragma unroll
    for (int j = 0; j < 4; ++j) st[j] = (f4v)0.0f;
    #pragma unroll
    for (int j = 0; j < 4; ++j)
      #pragma unroll
      for (int s = 0; s < 2; ++s) {
        s8v kf = *lds_frag(Ks, j * 16 + lr, s * 32 + lc * 8);
        st[j] = __builtin_amdgcn_mfma_f32_16x16x32_bf16(kf, qf[s], st[j], 0, 0, 0);
      }

    // tree max (short dep chains, max3-fusable)
    float mj[4];
    #pragma unroll
    for (int j = 0; j < 4; ++j)
      mj[j] = fmaxf(fmaxf(st[j][0], st[j][1]), fmaxf(st[j][2], st[j][3]));
    float pm = fmaxf(fmaxf(mj[0], mj[1]), fmaxf(mj[2], mj[3]));
    pm = fmaxf(pm, __shfl_xor(pm, 16));
    pm = fmaxf(pm, __shfl_xor(pm, 32));

    // T13 defer-max: rescale only when the wave sees real max growth
    if (!__all(pm <= Mx + 8.0f)) {
      const float Mn = fmaxf(Mx, pm);
      const float alpha = __expf(Mx - Mn);
      Ls *= alpha;
      float al[4];
      #pragma unroll
      for (int r = 0; r < 4; ++r) al[r] = __shfl(alpha, lc * 4 + r);
      #pragma unroll
      for (int jd = 0; jd < 4; ++jd)
        #pragma unroll
        for (int r = 0; r < 4; ++r) of[jd][r] *= al[r];
      Mx = Mn;
    }

    float rsj[4];
    #pragma unroll
    for (int j = 0; j < 4; ++j) {
      s4v pk;
      float pv[4];
      #pragma unroll
      for (int r = 0; r < 4; ++r) {
        pv[r] = __expf(st[j][r] - Mx);
        pk[r] = f2bf(pv[r]);
      }
      rsj[j] = (pv[0] + pv[1]) + (pv[2] + pv[3]);
      int byte = (lr << 7) + ((j * 16 + lc * 4) << 1);
      byte ^= ((lr & 7) << 4);
      *(s4v*)((char*)Pw + byte) = pk;
    }
    float rs = (rsj[0] + rsj[1]) + (rsj[2] + rsj[3]);
    rs += __shfl_xor(rs, 16);
    rs += __shfl_xor(rs, 32);
    Ls += rs;

    // ensure P ds_writes complete (and fence compiler ordering) before PV reads
    asm volatile("s_waitcnt lgkmcnt(0)" ::: "memory");

    // O += P * V
    #pragma unroll
    for (int s = 0; s < 2; ++s) {
      s8v pf = *lds_frag(Pw, lr, s * 32 + lc * 8);
      #pragma unroll
      for (int jd = 0; jd < 4; ++jd) {
        s8v vf = *lds_frag(Vt, jd * 16 + lr, s * 32 + lc * 8);
        of[jd] = __builtin_amdgcn_mfma_f32_16x16x32_bf16(pf, vf, of[jd], 0, 0, 0);
      }
    }
  }

  // store UNNORMALIZED partial O (f32) + per-row (m, l)
  float* OP = split ? OP1 : OP0;
  #pragma unroll
  for (int jd = 0; jd < 4; ++jd)
    #pragma unroll
    for (int r = 0; r < 4; ++r)
      OP[((size_t)bh * SEQ + q0 + lc * 4 + r) * HD + jd * 16 + lr] = of[jd][r];
  if (lc == 0) {
    float2 ml = make_float2(Mx, Ls);
    *reinterpret_cast<float2*>(
        &ML[((size_t)split * BD * NH * SEQ + (size_t)bh * SEQ + q0 + lr) * 2]) = ml;
  }
}

// ---------------- combine split halves -> AO bf16 (B,N,H*D) ----------------
__global__ __launch_bounds__(256) void k_comb(const float* __restrict__ OP0,
                                              const float* __restrict__ OP1,
                                              const float* __restrict__ ML,
                                              short* __restrict__ AO) {
  const int gid = blockIdx.x * 256 + threadIdx.x; // one (row, 16d-chunk) each
  const int row = gid >> 2, c = gid & 3;          // rows = 32*2048
  const int bh = row >> 11, q = row & (SEQ - 1);
  const float2 ml1 = *reinterpret_cast<const float2*>(&ML[(size_t)row * 2]);
  const float2 ml2 = *reinterpret_cast<const float2*>(
      &ML[((size_t)BD * NH * SEQ + row) * 2]);
  const float M = fmaxf(ml1.x, ml2.x);
  const float w1 = __expf(ml1.x - M), w2 = __expf(ml2.x - M);
  const float inv = 1.0f / (w1 * ml1.y + w2 * ml2.y);
  const int b = bh >> 4, h = bh & 15;
  short* dst = &AO[((size_t)(b * SEQ + q) * (NH * HD)) + h * HD + c * 16];
  const size_t src = (size_t)row * HD + c * 16;
  #pragma unroll
  for (int i = 0; i < 4; ++i) {
    float4 a = reinterpret_cast<const float4*>(&OP0[src])[i];
    float4 bvv = reinterpret_cast<const float4*>(&OP1[src])[i];
    s4v o;
    o[0] = f2bf((w1 * a.x + w2 * bvv.x) * inv);
    o[1] = f2bf((w1 * a.y + w2 * bvv.y) * inv);
    o[2] = f2bf((w1 * a.z + w2 * bvv.z) * inv);
    o[3] = f2bf((w1 * a.w + w2 * bvv.w) * inv);
    reinterpret_cast<s4v*>(dst)[i] = o;
  }
}

// ---------------- launch ----------------
extern "C" void kernel_launch(void* const* d_in, const int* in_sizes, int n_in,
                              void* d_out, int out_size, void* d_ws, size_t ws_size,
                              hipStream_t stream) {
  const float* x      = (const float*)d_in[0];
  const float* w_qkv  = (const float*)d_in[1];
  const float* b_qkv  = (const float*)d_in[2];
  const float* w_proj = (const float*)d_in[3];
  const float* b_proj = (const float*)d_in[4];
  float* out = (float*)d_out;

  char* ws = (char*)d_ws;
  short* wpT = (short*)(ws);                  //  2 MiB  w_proj^T bf16
  short* Qw  = (short*)(ws + (2u << 20));     //  8 MiB  Q (B,H,N,D) pre-scaled
  short* Kw  = (short*)(ws + (10u << 20));    //  8 MiB  K (B,H,N,D)
  short* Vtg = (short*)(ws + (18u << 20));    //  8 MiB  V^T (B,H,D,N)
  short* AO  = (short*)(ws + (26u << 20));    //  8 MiB  attn out bf16 (B,N,H*D)
  short* xb  = (short*)(ws + (34u << 20));    //  8 MiB  x bf16 [dead after GEMM0]
  short* wqT = (short*)(ws + (42u << 20));    //  6 MiB  w_qkv^T [dead after GEMM0]
  float* OP1 = (float*)(ws + (34u << 20));    // 16 MiB  attn partial 1 (overlay)
  float* ML  = (float*)(ws + (50u << 20));    //  1 MiB  (m,l) pairs, both splits
  float* OP0 = (float*)d_out;                 // 16 MiB  attn partial 0

  k_cast<<<(MROWS * IND / 4 + 255) / 256, 256, 0, stream>>>(x, xb, MROWS * IND / 4);
  dim3 tb(32, 8);
  k_transpose_cast<<<dim3(QKVD / 32, IND / 32), tb, 0, stream>>>(w_qkv, wqT, IND, QKVD);
  k_transpose_cast<<<dim3(IND / 32, IND / 32), tb, 0, stream>>>(w_proj, wpT, IND, IND);

  k_gemm<0><<<dim3(MROWS / 128, QKVD / 128), 256, 0, stream>>>(
      xb, wqT, b_qkv, Qw, nullptr, MROWS, QKVD, IND);
  k_attn<<<dim3(SEQ / 64, BD * NH, NSPLIT), 256, 0, stream>>>(Qw, Kw, Vtg, OP0, OP1, ML);
  k_comb<<<(BD * NH * SEQ * 4) / 256, 256, 0, stream>>>(OP0, OP1, ML, AO);
  k_gemm<1><<<dim3(MROWS / 128, IND / 128), 256, 0, stream>>>(
      AO, wpT, b_proj, nullptr, out, MROWS, IND, IND);
}